// Round 1
// baseline (1093.861 us; speedup 1.0000x reference)
//
#include <hip/hip_runtime.h>
#include <math.h>

#define N_TOK 1024
#define D_DIM 768
#define H_N   12
#define DH    64
#define DP    128
#define SCALE 0.125f
#define EPS   1e-5f
#define NN    (N_TOK * N_TOK)

// ---------------------------------------------------------------------------
// prep: W2[c,h] = pair_ln_w[c] * bias_W[c,h]
//       S2[h]   = sum_c W2[c,h]
//       cb[h]   = sum_c pair_ln_b[c] * bias_W[c,h] + bias_b[h]
// so that LN(p) . W_h == (p . W2_h - mean(p)*S2[h]) * rstd + cb[h]
// ---------------------------------------------------------------------------
__global__ __launch_bounds__(128) void prep_kernel(
    const float* __restrict__ pair_ln_w, const float* __restrict__ pair_ln_b,
    const float* __restrict__ bias_W, const float* __restrict__ bias_b,
    float* __restrict__ W2, float* __restrict__ S2cb)
{
    __shared__ float Ws[DP * H_N];
    __shared__ float slw[DP], slb[DP];
    int t = threadIdx.x; // 128 threads
    slw[t] = pair_ln_w[t];
    slb[t] = pair_ln_b[t];
    for (int idx = t; idx < DP * H_N; idx += 128) Ws[idx] = bias_W[idx];
    __syncthreads();
    for (int idx = t; idx < DP * H_N; idx += 128) {
        int c = idx / H_N;
        W2[idx] = slw[c] * Ws[idx];
    }
    if (t < 24) {
        int h = t % H_N;
        bool isS = t < H_N;
        float s = 0.f;
        for (int c = 0; c < DP; ++c)
            s += (isS ? slw[c] : slb[c]) * Ws[c * H_N + h];
        S2cb[t] = isS ? s : (s + bias_b[h]);
    }
}

// ---------------------------------------------------------------------------
// Row LayerNorm over 768 cols. One block (256 thr) per row, 3 elems/thread.
// Works in-place (block owns its whole row).
// ---------------------------------------------------------------------------
__global__ __launch_bounds__(256) void ln_kernel(
    const float* __restrict__ in, float* __restrict__ out,
    int istride, int ostride,
    const float* __restrict__ w, const float* __restrict__ b)
{
    int row = blockIdx.x;
    int tid = threadIdx.x;
    const float* ip = in + (size_t)row * istride;
    float v0 = ip[tid], v1 = ip[tid + 256], v2 = ip[tid + 512];
    float s = v0 + v1 + v2;
    float q = v0 * v0 + v1 * v1 + v2 * v2;
    __shared__ float red[8];
    #pragma unroll
    for (int o = 32; o > 0; o >>= 1) {
        s += __shfl_down(s, o);
        q += __shfl_down(q, o);
    }
    int lane = tid & 63, wv = tid >> 6;
    if (lane == 0) { red[wv] = s; red[4 + wv] = q; }
    __syncthreads();
    if (tid == 0) {
        float ss = red[0] + red[1] + red[2] + red[3];
        float qq = red[4] + red[5] + red[6] + red[7];
        float mean = ss * (1.f / 768.f);
        float var = qq * (1.f / 768.f) - mean * mean;
        red[0] = mean;
        red[1] = rsqrtf(var + EPS);
    }
    __syncthreads();
    float mean = red[0], rstd = red[1];
    float* op = out + (size_t)row * ostride;
    op[tid]       = (v0 - mean) * rstd * w[tid]       + b[tid];
    op[tid + 256] = (v1 - mean) * rstd * w[tid + 256] + b[tid + 256];
    op[tid + 512] = (v2 - mean) * rstd * w[tid + 512] + b[tid + 512];
}

// ---------------------------------------------------------------------------
// Tiled fp32 GEMM: C[M,N] = A[M,K] @ B + bias-row.  BM=64, BN=128, BK=16,
// 256 thr, 4x8 micro-tile. Column source switches from (B0,bias0) to
// (B1,bias1) at `split` (split % 128 == 0 so whole blocks are uniform).
// A-fragment LDS reads are 4-address broadcasts (ty 0-3 per wave); B reads
// 2-way (free); As scalar writes 2-way; Bs f4 writes perfectly spread.
// ---------------------------------------------------------------------------
__global__ __launch_bounds__(256) void sgemm(
    const float* __restrict__ A, int lda,
    const float* __restrict__ B0, int ldb0, const float* __restrict__ bias0,
    const float* __restrict__ B1, int ldb1, const float* __restrict__ bias1,
    int split, float* __restrict__ C, int ldc, int K)
{
    __shared__ __align__(16) float As[16 * 68];    // [k][m] transposed
    __shared__ __align__(16) float Bs[16 * 132];   // [k][n]
    int tid = threadIdx.x;
    int tx = tid & 15, ty = tid >> 4;
    int m0 = blockIdx.y * 64, n0 = blockIdx.x * 128;
    const float* Bp; const float* bp; int ldb, bcol0;
    if (n0 < split) { Bp = B0; bp = bias0; ldb = ldb0; bcol0 = n0; }
    else            { Bp = B1; bp = bias1; ldb = ldb1; bcol0 = n0 - split; }

    float acc[4][8] = {};
    int ar = tid >> 2, ak = (tid & 3) * 4;   // A loader: 64 rows x 4 f4(k)
    int bk = tid >> 5, bc = (tid & 31) * 4;  // B loader: 8 k x 32 f4(n), x2

    for (int kt = 0; kt < K; kt += 16) {
        float4 av  = *(const float4*)&A[(size_t)(m0 + ar) * lda + kt + ak];
        float4 b0v = *(const float4*)&Bp[(size_t)(kt + bk) * ldb + bcol0 + bc];
        float4 b1v = *(const float4*)&Bp[(size_t)(kt + bk + 8) * ldb + bcol0 + bc];
        As[(ak + 0) * 68 + ar] = av.x;
        As[(ak + 1) * 68 + ar] = av.y;
        As[(ak + 2) * 68 + ar] = av.z;
        As[(ak + 3) * 68 + ar] = av.w;
        *(float4*)&Bs[bk * 132 + bc] = b0v;
        *(float4*)&Bs[(bk + 8) * 132 + bc] = b1v;
        __syncthreads();
        #pragma unroll
        for (int kk = 0; kk < 16; ++kk) {
            float4 a  = *(const float4*)&As[kk * 68 + ty * 4];
            float4 b0 = *(const float4*)&Bs[kk * 132 + tx * 4];
            float4 b1 = *(const float4*)&Bs[kk * 132 + 64 + tx * 4];
            float av_[4] = { a.x, a.y, a.z, a.w };
            float bv_[8] = { b0.x, b0.y, b0.z, b0.w, b1.x, b1.y, b1.z, b1.w };
            #pragma unroll
            for (int u = 0; u < 4; ++u)
                #pragma unroll
                for (int i = 0; i < 8; ++i)
                    acc[u][i] += av_[u] * bv_[i];
        }
        __syncthreads();
    }
    float4 bb0 = *(const float4*)&bp[bcol0 + tx * 4];
    float4 bb1 = *(const float4*)&bp[bcol0 + 64 + tx * 4];
    #pragma unroll
    for (int u = 0; u < 4; ++u) {
        float* cp = &C[(size_t)(m0 + ty * 4 + u) * ldc + n0];
        float4 o0, o1;
        o0.x = acc[u][0] + bb0.x; o0.y = acc[u][1] + bb0.y;
        o0.z = acc[u][2] + bb0.z; o0.w = acc[u][3] + bb0.w;
        o1.x = acc[u][4] + bb1.x; o1.y = acc[u][5] + bb1.y;
        o1.z = acc[u][6] + bb1.z; o1.w = acc[u][7] + bb1.w;
        *(float4*)&cp[tx * 4]      = o0;
        *(float4*)&cp[64 + tx * 4] = o1;
    }
}

// ---------------------------------------------------------------------------
// bias[h,i,j] = (p[i,j,:].W2_h - mean*S2_h)*rstd + cb_h + (mask? 0 : -1e4)
// One thread per (i,j). W2 rows are 48B-aligned -> 3 float4 broadcast LDS
// reads per channel instead of 12 scalar reads.
// ---------------------------------------------------------------------------
__global__ __launch_bounds__(256) void bias_kernel(
    const float* __restrict__ pair, const int* __restrict__ mask,
    const float* __restrict__ W2, const float* __restrict__ S2cb,
    float* __restrict__ biasbuf)
{
    __shared__ __align__(16) float sW2[DP * H_N];
    __shared__ float sS[H_N], sC[H_N];
    int tid = threadIdx.x;
    for (int t = tid; t < DP * H_N; t += 256) sW2[t] = W2[t];
    if (tid < H_N) { sS[tid] = S2cb[tid]; sC[tid] = S2cb[H_N + tid]; }
    __syncthreads();

    int gid = blockIdx.x * 256 + tid;           // gid = i*1024 + j
    const float4* p4 = (const float4*)(pair + (size_t)gid * DP);
    float sum = 0.f, ssq = 0.f;
    float dot[H_N];
    #pragma unroll
    for (int h = 0; h < H_N; ++h) dot[h] = 0.f;

    #pragma unroll 4
    for (int c4 = 0; c4 < 32; ++c4) {
        float4 v = p4[c4];
        float e[4] = { v.x, v.y, v.z, v.w };
        #pragma unroll
        for (int k = 0; k < 4; ++k) {
            float x = e[k];
            sum += x; ssq += x * x;
            const float4* wp4 = (const float4*)&sW2[(c4 * 4 + k) * H_N];
            float4 w0 = wp4[0], w1 = wp4[1], w2 = wp4[2];
            dot[0] += x * w0.x; dot[1] += x * w0.y; dot[2]  += x * w0.z; dot[3]  += x * w0.w;
            dot[4] += x * w1.x; dot[5] += x * w1.y; dot[6]  += x * w1.z; dot[7]  += x * w1.w;
            dot[8] += x * w2.x; dot[9] += x * w2.y; dot[10] += x * w2.z; dot[11] += x * w2.w;
        }
    }
    float mean = sum * (1.f / 128.f);
    float var  = ssq * (1.f / 128.f) - mean * mean;
    float rstd = rsqrtf(var + EPS);
    float mz = (mask[gid] != 0) ? 0.f : -10000.f;
    #pragma unroll
    for (int h = 0; h < H_N; ++h)
        biasbuf[(size_t)h * NN + gid] = (dot[h] - mean * sS[h]) * rstd + sC[h] + mz;
}

// ---------------------------------------------------------------------------
// Flash attention per (head, 16-row tile). Bc=32 K/V tiles via LDS, online
// softmax, sigmoid(g) gating fused in epilogue.
// K tile stored with XOR-swizzled float4 granules (col ^ ((row>>1)&7)) at
// unpadded stride 64: row-reads at fixed col hit 8 distinct 4-bank groups
// (2-way = free) instead of 4-way; writes remain perfectly spread.
// QK^T inner loop: 3 ds_read_b128 per 4 d (was 12 ds_read_b32).
// xw layout per row: [ q(768, LN'd) | k(768, LN'd) | v(768) | g(768) ]
// ---------------------------------------------------------------------------
__global__ __launch_bounds__(256) void attn_kernel(
    const float* __restrict__ xw, const float* __restrict__ biasbuf,
    float* __restrict__ attn_out)
{
    const int h  = blockIdx.y;
    const int i0 = blockIdx.x * 16;
    const int tid = threadIdx.x;
    const int tx = tid & 15, ty = tid >> 4;

    __shared__ __align__(16) float Qs[16 * 68];
    __shared__ __align__(16) float Ks[32 * 64];   // swizzled
    __shared__ __align__(16) float Vs[32 * 68];
    __shared__ float Ps[16 * 33];

    {   // stage Q (scale folded)
        int r = tid >> 4, c4 = tid & 15;
        float4 v = *(const float4*)(xw + (size_t)(i0 + r) * 3072 + h * 64 + c4 * 4);
        float* d = &Qs[r * 68 + c4 * 4];
        d[0] = v.x * SCALE; d[1] = v.y * SCALE; d[2] = v.z * SCALE; d[3] = v.w * SCALE;
    }

    float m = -1e30f, l = 0.f;
    float a0 = 0.f, a1 = 0.f, a2 = 0.f, a3 = 0.f;
    const float* brow = biasbuf + (size_t)h * NN + (size_t)(i0 + ty) * N_TOK;
    const int swz = tx & 7;
    const float* qrow = &Qs[ty * 68];
    const float* k0p = &Ks[(2 * tx) << 6];
    const float* k1p = &Ks[((2 * tx) << 6) + 64];

    for (int j0 = 0; j0 < N_TOK; j0 += 32) {
        #pragma unroll
        for (int q2 = 0; q2 < 2; ++q2) {       // stage K, V tiles (32x64)
            int idx = tid + q2 * 256;
            int r = idx >> 4, c4 = idx & 15;
            const float* gp = xw + (size_t)(j0 + r) * 3072 + 768 + h * 64 + c4 * 4;
            float4 kv = *(const float4*)gp;
            *(float4*)&Ks[(r << 6) + ((c4 ^ ((r >> 1) & 7)) << 2)] = kv;
            float4 vv = *(const float4*)(gp + 768);
            *(float4*)&Vs[r * 68 + c4 * 4] = vv;
        }
        __syncthreads();

        // S: each thread -> row ty, cols {2tx, 2tx+1}; float4 LDS reads
        float s0a = 0.f, s0b = 0.f, s1a = 0.f, s1b = 0.f;
        #pragma unroll
        for (int d4 = 0; d4 < 16; ++d4) {
            float4 q  = *(const float4*)&qrow[d4 << 2];
            int o = (d4 ^ swz) << 2;
            float4 ka = *(const float4*)&k0p[o];
            float4 kb = *(const float4*)&k1p[o];
            s0a += q.x * ka.x + q.y * ka.y;
            s0b += q.z * ka.z + q.w * ka.w;
            s1a += q.x * kb.x + q.y * kb.y;
            s1b += q.z * kb.z + q.w * kb.w;
        }
        float2 bb = *(const float2*)&brow[j0 + 2 * tx];
        float s0 = s0a + s0b + bb.x;
        float s1 = s1a + s1b + bb.y;

        // online softmax (reduce across the 16 tx lanes of this row)
        float mt = fmaxf(s0, s1);
        #pragma unroll
        for (int o = 1; o < 16; o <<= 1) mt = fmaxf(mt, __shfl_xor(mt, o));
        float mn = fmaxf(m, mt);
        float al = __expf(m - mn);
        float p0 = __expf(s0 - mn);
        float p1 = __expf(s1 - mn);
        float rs = p0 + p1;
        #pragma unroll
        for (int o = 1; o < 16; o <<= 1) rs += __shfl_xor(rs, o);
        l = l * al + rs;
        m = mn;
        a0 *= al; a1 *= al; a2 *= al; a3 *= al;
        Ps[ty * 33 + 2 * tx]     = p0;
        Ps[ty * 33 + 2 * tx + 1] = p1;
        __syncthreads();

        // O: row ty, d-cols {4tx..4tx+3}
        const float* prow = &Ps[ty * 33];
        #pragma unroll
        for (int j = 0; j < 32; ++j) {
            float pv = prow[j];
            float4 vv = *(const float4*)&Vs[j * 68 + tx * 4];
            a0 += pv * vv.x; a1 += pv * vv.y; a2 += pv * vv.z; a3 += pv * vv.w;
        }
        __syncthreads();
    }

    float inv = 1.f / l;
    int row = i0 + ty;
    float4 gv = *(const float4*)(xw + (size_t)row * 3072 + 2304 + h * 64 + tx * 4);
    float* op = attn_out + (size_t)row * 768 + h * 64 + tx * 4;
    op[0] = a0 * inv / (1.f + __expf(-gv.x));
    op[1] = a1 * inv / (1.f + __expf(-gv.y));
    op[2] = a2 * inv / (1.f + __expf(-gv.z));
    op[3] = a3 * inv / (1.f + __expf(-gv.w));
}

// ---------------------------------------------------------------------------
extern "C" void kernel_launch(void* const* d_in, const int* in_sizes, int n_in,
                              void* d_out, int out_size, void* d_ws, size_t ws_size,
                              hipStream_t stream)
{
    const float* node      = (const float*)d_in[0];
    const float* pair      = (const float*)d_in[1];
    const float* ln_node_w = (const float*)d_in[2];
    const float* ln_node_b = (const float*)d_in[3];
    const float* pair_ln_w = (const float*)d_in[4];
    const float* pair_ln_b = (const float*)d_in[5];
    const float* qkv_W     = (const float*)d_in[6];
    const float* qkv_b     = (const float*)d_in[7];
    const float* q_ln_w    = (const float*)d_in[8];
    const float* q_ln_b    = (const float*)d_in[9];
    const float* k_ln_w    = (const float*)d_in[10];
    const float* k_ln_b    = (const float*)d_in[11];
    const float* g_W       = (const float*)d_in[12];
    const float* g_b       = (const float*)d_in[13];
    const float* bias_W    = (const float*)d_in[14];
    const float* bias_b    = (const float*)d_in[15];
    const float* out_W     = (const float*)d_in[16];
    const float* out_b     = (const float*)d_in[17];
    const int*   mask      = (const int*)d_in[18]; // jax bool delivered as int32
    float* out = (float*)d_out;

    float* ws      = (float*)d_ws;
    float* x       = ws;                   // 1024*768
    float* xw      = x + 786432;           // 1024*3072  [q|k|v|g]
    float* W2      = xw + 3145728;         // 128*12
    float* S2cb    = W2 + 1536;            // 24 (padded 32)
    float* biasbuf = S2cb + 32;            // 12*1024*1024
    float* attn_o  = biasbuf + 12582912;   // 1024*768

    prep_kernel<<<1, 128, 0, stream>>>(pair_ln_w, pair_ln_b, bias_W, bias_b, W2, S2cb);
    ln_kernel<<<1024, 256, 0, stream>>>(node, x, 768, 768, ln_node_w, ln_node_b);
    sgemm<<<dim3(24, 16), 256, 0, stream>>>(x, 768,
                                            qkv_W, 2304, qkv_b,
                                            g_W, 768, g_b,
                                            2304, xw, 3072, 768);
    ln_kernel<<<1024, 256, 0, stream>>>(xw, xw, 3072, 3072, q_ln_w, q_ln_b);
    ln_kernel<<<1024, 256, 0, stream>>>(xw + 768, xw + 768, 3072, 3072, k_ln_w, k_ln_b);
    bias_kernel<<<4096, 256, 0, stream>>>(pair, mask, W2, S2cb, biasbuf);
    attn_kernel<<<dim3(64, 12), 256, 0, stream>>>(xw, biasbuf, attn_o);
    sgemm<<<dim3(6, 16), 256, 0, stream>>>(attn_o, 768,
                                           out_W, 768, out_b,
                                           out_W, 768, out_b,
                                           1 << 30, out, 768, 768);
}

// Round 2
// 1032.990 us; speedup vs baseline: 1.0589x; 1.0589x over previous
//
#include <hip/hip_runtime.h>
#include <math.h>

#define N_TOK 1024
#define D_DIM 768
#define H_N   12
#define DH    64
#define DP    128
#define SCALE 0.125f
#define EPS   1e-5f
#define NN    (N_TOK * N_TOK)

// ---------------------------------------------------------------------------
// prep: W2[c,h] = pair_ln_w[c] * bias_W[c,h]
//       S2[h]   = sum_c W2[c,h]
//       cb[h]   = sum_c pair_ln_b[c] * bias_W[c,h] + bias_b[h]
// so that LN(p) . W_h == (p . W2_h - mean(p)*S2[h]) * rstd + cb[h]
// ---------------------------------------------------------------------------
__global__ __launch_bounds__(128) void prep_kernel(
    const float* __restrict__ pair_ln_w, const float* __restrict__ pair_ln_b,
    const float* __restrict__ bias_W, const float* __restrict__ bias_b,
    float* __restrict__ W2, float* __restrict__ S2cb)
{
    __shared__ float Ws[DP * H_N];
    __shared__ float slw[DP], slb[DP];
    int t = threadIdx.x; // 128 threads
    slw[t] = pair_ln_w[t];
    slb[t] = pair_ln_b[t];
    for (int idx = t; idx < DP * H_N; idx += 128) Ws[idx] = bias_W[idx];
    __syncthreads();
    for (int idx = t; idx < DP * H_N; idx += 128) {
        int c = idx / H_N;
        W2[idx] = slw[c] * Ws[idx];
    }
    if (t < 24) {
        int h = t % H_N;
        bool isS = t < H_N;
        float s = 0.f;
        for (int c = 0; c < DP; ++c)
            s += (isS ? slw[c] : slb[c]) * Ws[c * H_N + h];
        S2cb[t] = isS ? s : (s + bias_b[h]);
    }
}

// ---------------------------------------------------------------------------
// Row LayerNorm over 768 cols. One block (256 thr) per row, 3 elems/thread.
// ---------------------------------------------------------------------------
__global__ __launch_bounds__(256) void ln_kernel(
    const float* __restrict__ in, float* __restrict__ out,
    int istride, int ostride,
    const float* __restrict__ w, const float* __restrict__ b)
{
    int row = blockIdx.x;
    int tid = threadIdx.x;
    const float* ip = in + (size_t)row * istride;
    float v0 = ip[tid], v1 = ip[tid + 256], v2 = ip[tid + 512];
    float s = v0 + v1 + v2;
    float q = v0 * v0 + v1 * v1 + v2 * v2;
    __shared__ float red[8];
    #pragma unroll
    for (int o = 32; o > 0; o >>= 1) {
        s += __shfl_down(s, o);
        q += __shfl_down(q, o);
    }
    int lane = tid & 63, wv = tid >> 6;
    if (lane == 0) { red[wv] = s; red[4 + wv] = q; }
    __syncthreads();
    if (tid == 0) {
        float ss = red[0] + red[1] + red[2] + red[3];
        float qq = red[4] + red[5] + red[6] + red[7];
        float mean = ss * (1.f / 768.f);
        float var = qq * (1.f / 768.f) - mean * mean;
        red[0] = mean;
        red[1] = rsqrtf(var + EPS);
    }
    __syncthreads();
    float mean = red[0], rstd = red[1];
    float* op = out + (size_t)row * ostride;
    op[tid]       = (v0 - mean) * rstd * w[tid]       + b[tid];
    op[tid + 256] = (v1 - mean) * rstd * w[tid + 256] + b[tid + 256];
    op[tid + 512] = (v2 - mean) * rstd * w[tid + 512] + b[tid + 512];
}

// ---------------------------------------------------------------------------
// Tiled fp32 GEMM: C[M,N] = A[M,K] @ B + bias-row.  BM=64, BN=128, BK=16,
// 256 thr, 4x8 micro-tile. Column source switches at `split` (mult of 128).
// ---------------------------------------------------------------------------
__global__ __launch_bounds__(256) void sgemm(
    const float* __restrict__ A, int lda,
    const float* __restrict__ B0, int ldb0, const float* __restrict__ bias0,
    const float* __restrict__ B1, int ldb1, const float* __restrict__ bias1,
    int split, float* __restrict__ C, int ldc, int K)
{
    __shared__ __align__(16) float As[16 * 68];    // [k][m] transposed
    __shared__ __align__(16) float Bs[16 * 132];   // [k][n]
    int tid = threadIdx.x;
    int tx = tid & 15, ty = tid >> 4;
    int m0 = blockIdx.y * 64, n0 = blockIdx.x * 128;
    const float* Bp; const float* bp; int ldb, bcol0;
    if (n0 < split) { Bp = B0; bp = bias0; ldb = ldb0; bcol0 = n0; }
    else            { Bp = B1; bp = bias1; ldb = ldb1; bcol0 = n0 - split; }

    float acc[4][8] = {};
    int ar = tid >> 2, ak = (tid & 3) * 4;   // A loader: 64 rows x 4 f4(k)
    int bk = tid >> 5, bc = (tid & 31) * 4;  // B loader: 8 k x 32 f4(n), x2

    for (int kt = 0; kt < K; kt += 16) {
        float4 av  = *(const float4*)&A[(size_t)(m0 + ar) * lda + kt + ak];
        float4 b0v = *(const float4*)&Bp[(size_t)(kt + bk) * ldb + bcol0 + bc];
        float4 b1v = *(const float4*)&Bp[(size_t)(kt + bk + 8) * ldb + bcol0 + bc];
        As[(ak + 0) * 68 + ar] = av.x;
        As[(ak + 1) * 68 + ar] = av.y;
        As[(ak + 2) * 68 + ar] = av.z;
        As[(ak + 3) * 68 + ar] = av.w;
        *(float4*)&Bs[bk * 132 + bc] = b0v;
        *(float4*)&Bs[(bk + 8) * 132 + bc] = b1v;
        __syncthreads();
        #pragma unroll
        for (int kk = 0; kk < 16; ++kk) {
            float4 a  = *(const float4*)&As[kk * 68 + ty * 4];
            float4 b0 = *(const float4*)&Bs[kk * 132 + tx * 4];
            float4 b1 = *(const float4*)&Bs[kk * 132 + 64 + tx * 4];
            float av_[4] = { a.x, a.y, a.z, a.w };
            float bv_[8] = { b0.x, b0.y, b0.z, b0.w, b1.x, b1.y, b1.z, b1.w };
            #pragma unroll
            for (int u = 0; u < 4; ++u)
                #pragma unroll
                for (int i = 0; i < 8; ++i)
                    acc[u][i] += av_[u] * bv_[i];
        }
        __syncthreads();
    }
    float4 bb0 = *(const float4*)&bp[bcol0 + tx * 4];
    float4 bb1 = *(const float4*)&bp[bcol0 + 64 + tx * 4];
    #pragma unroll
    for (int u = 0; u < 4; ++u) {
        float* cp = &C[(size_t)(m0 + ty * 4 + u) * ldc + n0];
        float4 o0, o1;
        o0.x = acc[u][0] + bb0.x; o0.y = acc[u][1] + bb0.y;
        o0.z = acc[u][2] + bb0.z; o0.w = acc[u][3] + bb0.w;
        o1.x = acc[u][4] + bb1.x; o1.y = acc[u][5] + bb1.y;
        o1.z = acc[u][6] + bb1.z; o1.w = acc[u][7] + bb1.w;
        *(float4*)&cp[tx * 4]      = o0;
        *(float4*)&cp[64 + tx * 4] = o1;
    }
}

// ---------------------------------------------------------------------------
// bias[h,i,j] = (p[i,j,:].W2_h - mean*S2_h)*rstd + cb_h + (mask? 0 : -1e4)
// Wave-cooperative: stage 64 contiguous pair rows (32 KB) into LDS with
// perfectly coalesced 1 KB/instr global loads; redistribute 4 lanes/row
// (32 strided channels each, +2*row XOR swizzle: 2-way / data-minimum on
// all LDS ops); butterfly-reduce {sum,ssq,dot[12]} over the 4-lane group;
// lane q writes heads 3q..3q+2.
// ---------------------------------------------------------------------------
__global__ __launch_bounds__(256) void bias_kernel(
    const float* __restrict__ pair, const int* __restrict__ mask,
    const float* __restrict__ W2, const float* __restrict__ S2cb,
    float* __restrict__ biasbuf)
{
    __shared__ __align__(16) float4 Lp[64 * 32];   // 32 KB staging
    __shared__ __align__(16) float sW2[DP * H_N];
    __shared__ float sS[H_N], sC[H_N];
    int tid = threadIdx.x;
    for (int t = tid; t < DP * H_N; t += 256) sW2[t] = W2[t];
    if (tid < H_N) { sS[tid] = S2cb[tid]; sC[tid] = S2cb[H_N + tid]; }

    int r = tid >> 2, qq = tid & 3;
    const float4* pair4 = (const float4*)pair;

    for (int c = 0; c < 4; ++c) {
        int gid0 = (blockIdx.x * 4 + c) * 64;
        __syncthreads();   // Lp safe to overwrite (also covers sW2 on c==0)
        #pragma unroll
        for (int i = 0; i < 8; ++i) {
            int n = i * 256 + tid;
            int row = n >> 5, c4 = n & 31;
            Lp[row * 32 + ((c4 + 2 * row) & 31)] = pair4[(size_t)gid0 * 32 + n];
        }
        __syncthreads();

        float sum = 0.f, ssq = 0.f;
        float dot[H_N];
        #pragma unroll
        for (int h = 0; h < H_N; ++h) dot[h] = 0.f;

        #pragma unroll
        for (int i = 0; i < 8; ++i) {
            int c4 = qq + 4 * i;                       // strided channel-f4
            float4 v = Lp[r * 32 + ((c4 + 2 * r) & 31)];
            float e[4] = { v.x, v.y, v.z, v.w };
            #pragma unroll
            for (int k = 0; k < 4; ++k) {
                float x = e[k];
                sum += x; ssq += x * x;
                const float4* wp4 = (const float4*)&sW2[(c4 * 4 + k) * H_N];
                float4 w0 = wp4[0], w1 = wp4[1], w2 = wp4[2];
                dot[0] += x * w0.x; dot[1] += x * w0.y; dot[2]  += x * w0.z; dot[3]  += x * w0.w;
                dot[4] += x * w1.x; dot[5] += x * w1.y; dot[6]  += x * w1.z; dot[7]  += x * w1.w;
                dot[8] += x * w2.x; dot[9] += x * w2.y; dot[10] += x * w2.z; dot[11] += x * w2.w;
            }
        }
        #pragma unroll
        for (int o = 1; o < 4; o <<= 1) {
            sum += __shfl_xor(sum, o);
            ssq += __shfl_xor(ssq, o);
            #pragma unroll
            for (int h = 0; h < H_N; ++h) dot[h] += __shfl_xor(dot[h], o);
        }
        float mean = sum * (1.f / 128.f);
        float var  = ssq * (1.f / 128.f) - mean * mean;
        float rstd = rsqrtf(var + EPS);
        float mz = (mask[gid0 + r] != 0) ? 0.f : -10000.f;
        #pragma unroll
        for (int s = 0; s < 3; ++s) {
            int h = qq * 3 + s;
            biasbuf[(size_t)h * NN + gid0 + r] = (dot[h] - mean * sS[h]) * rstd + sC[h] + mz;
        }
    }
}

// ---------------------------------------------------------------------------
// Flash attention per (head, 16-row tile). Bc=64 K/V tiles (half the
// barriers of Bc=32), 2x2 q-x-j micro-tile in QK (each K fragment serves
// 2 q-rows -> K LDS traffic per S-elem -33%). Online softmax per row over
// the 32 tj lanes; al/l relayed to the PV thread-mapping via LDS.
// xw layout per row: [ q(768, LN'd) | k(768, LN'd) | v(768) | g(768) ]
// ---------------------------------------------------------------------------
__global__ __launch_bounds__(256) void attn_kernel(
    const float* __restrict__ xw, const float* __restrict__ biasbuf,
    float* __restrict__ attn_out)
{
    const int h  = blockIdx.y;
    const int i0 = blockIdx.x * 16;
    const int tid = threadIdx.x;

    __shared__ __align__(16) float Qs[16 * 68];
    __shared__ __align__(16) float Ks[64 * 64];   // XOR-swizzled f4 granules
    __shared__ __align__(16) float Vs[64 * 68];
    __shared__ float Ps[16 * 68];
    __shared__ float alrow[16], lfin[16];

    {   // stage Q (scale folded)
        int r = tid >> 4, c4 = tid & 15;
        float4 v = *(const float4*)(xw + (size_t)(i0 + r) * 3072 + h * 64 + c4 * 4);
        float* d = &Qs[r * 68 + c4 * 4];
        d[0] = v.x * SCALE; d[1] = v.y * SCALE; d[2] = v.z * SCALE; d[3] = v.w * SCALE;
    }

    // QK mapping: thread (tq, tj) owns S rows {2tq,2tq+1} x cols {2tj,2tj+1}
    const int tj = tid & 31, tq = tid >> 5;
    const float* q0p = &Qs[(2 * tq) * 68];
    const float* q1p = q0p + 68;
    const float* k0p = &Ks[(2 * tj) << 6];
    const float* k1p = k0p + 64;
    const int swz = tj & 7;
    const float* brow0 = biasbuf + (size_t)h * NN + (size_t)(i0 + 2 * tq) * N_TOK;
    const float* brow1 = brow0 + N_TOK;
    // PV mapping: thread (tx, ty) owns O row ty x d-cols {4tx..4tx+3}
    const int tx = tid & 15, ty = tid >> 4;

    float m0r = -1e30f, m1r = -1e30f, l0 = 0.f, l1 = 0.f;
    float a0 = 0.f, a1 = 0.f, a2 = 0.f, a3 = 0.f;

    for (int j0 = 0; j0 < N_TOK; j0 += 64) {
        #pragma unroll
        for (int q2 = 0; q2 < 4; ++q2) {       // stage K, V tiles (64x64)
            int idx = q2 * 256 + tid;
            int rr = idx >> 4, c4 = idx & 15;
            const float* gp = xw + (size_t)(j0 + rr) * 3072 + 768 + h * 64 + c4 * 4;
            float4 kv = *(const float4*)gp;
            *(float4*)&Ks[(rr << 6) + ((c4 ^ ((rr >> 1) & 7)) << 2)] = kv;
            float4 vv = *(const float4*)(gp + 768);
            *(float4*)&Vs[rr * 68 + c4 * 4] = vv;
        }
        __syncthreads();

        // QK 2x2 micro-tile, float4 accumulators
        float4 s00 = {0,0,0,0}, s01 = {0,0,0,0}, s10 = {0,0,0,0}, s11 = {0,0,0,0};
        #pragma unroll
        for (int d4 = 0; d4 < 16; ++d4) {
            float4 qa = *(const float4*)&q0p[d4 << 2];
            float4 qb = *(const float4*)&q1p[d4 << 2];
            int o = (d4 ^ swz) << 2;
            float4 ka = *(const float4*)&k0p[o];
            float4 kb = *(const float4*)&k1p[o];
            s00.x += qa.x * ka.x; s00.y += qa.y * ka.y; s00.z += qa.z * ka.z; s00.w += qa.w * ka.w;
            s01.x += qa.x * kb.x; s01.y += qa.y * kb.y; s01.z += qa.z * kb.z; s01.w += qa.w * kb.w;
            s10.x += qb.x * ka.x; s10.y += qb.y * ka.y; s10.z += qb.z * ka.z; s10.w += qb.w * ka.w;
            s11.x += qb.x * kb.x; s11.y += qb.y * kb.y; s11.z += qb.z * kb.z; s11.w += qb.w * kb.w;
        }
        float2 b0 = *(const float2*)&brow0[j0 + 2 * tj];
        float2 b1 = *(const float2*)&brow1[j0 + 2 * tj];
        float S00 = s00.x + s00.y + s00.z + s00.w + b0.x;
        float S01 = s01.x + s01.y + s01.z + s01.w + b0.y;
        float S10 = s10.x + s10.y + s10.z + s10.w + b1.x;
        float S11 = s11.x + s11.y + s11.z + s11.w + b1.y;

        // online softmax: reduce over the 32 tj lanes (per row)
        float mt0 = fmaxf(S00, S01), mt1 = fmaxf(S10, S11);
        #pragma unroll
        for (int o = 1; o < 32; o <<= 1) {
            mt0 = fmaxf(mt0, __shfl_xor(mt0, o));
            mt1 = fmaxf(mt1, __shfl_xor(mt1, o));
        }
        float mn0 = fmaxf(m0r, mt0), mn1 = fmaxf(m1r, mt1);
        float al0 = __expf(m0r - mn0), al1 = __expf(m1r - mn1);
        float p00 = __expf(S00 - mn0), p01 = __expf(S01 - mn0);
        float p10 = __expf(S10 - mn1), p11 = __expf(S11 - mn1);
        float rs0 = p00 + p01, rs1 = p10 + p11;
        #pragma unroll
        for (int o = 1; o < 32; o <<= 1) {
            rs0 += __shfl_xor(rs0, o);
            rs1 += __shfl_xor(rs1, o);
        }
        l0 = l0 * al0 + rs0; l1 = l1 * al1 + rs1;
        m0r = mn0; m1r = mn1;
        *(float2*)&Ps[(2 * tq) * 68 + 2 * tj]     = make_float2(p00, p01);
        *(float2*)&Ps[(2 * tq + 1) * 68 + 2 * tj] = make_float2(p10, p11);
        if (tj == 0) { alrow[2 * tq] = al0; alrow[2 * tq + 1] = al1; }
        __syncthreads();

        // PV: row ty, d-cols {4tx..4tx+3}
        float als = alrow[ty];
        a0 *= als; a1 *= als; a2 *= als; a3 *= als;
        const float* prow = &Ps[ty * 68];
        #pragma unroll
        for (int j = 0; j < 64; ++j) {
            float pv = prow[j];
            float4 vv = *(const float4*)&Vs[j * 68 + tx * 4];
            a0 += pv * vv.x; a1 += pv * vv.y; a2 += pv * vv.z; a3 += pv * vv.w;
        }
        __syncthreads();
    }

    if (tj == 0) { lfin[2 * tq] = l0; lfin[2 * tq + 1] = l1; }
    __syncthreads();

    float inv = 1.f / lfin[ty];
    int row = i0 + ty;
    float4 gv = *(const float4*)(xw + (size_t)row * 3072 + 2304 + h * 64 + tx * 4);
    float* op = attn_out + (size_t)row * 768 + h * 64 + tx * 4;
    op[0] = a0 * inv / (1.f + __expf(-gv.x));
    op[1] = a1 * inv / (1.f + __expf(-gv.y));
    op[2] = a2 * inv / (1.f + __expf(-gv.z));
    op[3] = a3 * inv / (1.f + __expf(-gv.w));
}

// ---------------------------------------------------------------------------
extern "C" void kernel_launch(void* const* d_in, const int* in_sizes, int n_in,
                              void* d_out, int out_size, void* d_ws, size_t ws_size,
                              hipStream_t stream)
{
    const float* node      = (const float*)d_in[0];
    const float* pair      = (const float*)d_in[1];
    const float* ln_node_w = (const float*)d_in[2];
    const float* ln_node_b = (const float*)d_in[3];
    const float* pair_ln_w = (const float*)d_in[4];
    const float* pair_ln_b = (const float*)d_in[5];
    const float* qkv_W     = (const float*)d_in[6];
    const float* qkv_b     = (const float*)d_in[7];
    const float* q_ln_w    = (const float*)d_in[8];
    const float* q_ln_b    = (const float*)d_in[9];
    const float* k_ln_w    = (const float*)d_in[10];
    const float* k_ln_b    = (const float*)d_in[11];
    const float* g_W       = (const float*)d_in[12];
    const float* g_b       = (const float*)d_in[13];
    const float* bias_W    = (const float*)d_in[14];
    const float* bias_b    = (const float*)d_in[15];
    const float* out_W     = (const float*)d_in[16];
    const float* out_b     = (const float*)d_in[17];
    const int*   mask      = (const int*)d_in[18]; // jax bool delivered as int32
    float* out = (float*)d_out;

    float* ws      = (float*)d_ws;
    float* x       = ws;                   // 1024*768
    float* xw      = x + 786432;           // 1024*3072  [q|k|v|g]
    float* W2      = xw + 3145728;         // 128*12
    float* S2cb    = W2 + 1536;            // 24 (padded 32)
    float* biasbuf = S2cb + 32;            // 12*1024*1024
    float* attn_o  = biasbuf + 12582912;   // 1024*768

    prep_kernel<<<1, 128, 0, stream>>>(pair_ln_w, pair_ln_b, bias_W, bias_b, W2, S2cb);
    ln_kernel<<<1024, 256, 0, stream>>>(node, x, 768, 768, ln_node_w, ln_node_b);
    sgemm<<<dim3(24, 16), 256, 0, stream>>>(x, 768,
                                            qkv_W, 2304, qkv_b,
                                            g_W, 768, g_b,
                                            2304, xw, 3072, 768);
    ln_kernel<<<1024, 256, 0, stream>>>(xw, xw, 3072, 3072, q_ln_w, q_ln_b);
    ln_kernel<<<1024, 256, 0, stream>>>(xw + 768, xw + 768, 3072, 3072, k_ln_w, k_ln_b);
    bias_kernel<<<4096, 256, 0, stream>>>(pair, mask, W2, S2cb, biasbuf);
    attn_kernel<<<dim3(64, 12), 256, 0, stream>>>(xw, biasbuf, attn_o);
    sgemm<<<dim3(6, 16), 256, 0, stream>>>(attn_o, 768,
                                           out_W, 768, out_b,
                                           out_W, 768, out_b,
                                           1 << 30, out, 768, 768);
}